// Round 20
// baseline (95.385 us; speedup 1.0000x reference)
//
#include <hip/hip_runtime.h>

// Problem constants
#define BB 4
#define RR 384
#define CC 384
#define EE 512
#define HH 16
#define DD 32
#define MROWS 1536   // B*R = B*C
#define MAXE 128     // edge-list stride (nE ~ 38 +- 6; 128 = 15 sigma)

typedef __attribute__((ext_vector_type(8))) short bf16x8;   // 8 bf16 = 4 VGPRs
typedef __attribute__((ext_vector_type(4))) float f32x4;

// ---------------------------------------------------------------------------
// f32 -> (hi, lo) bf16 split, RNE both times. x ~= hi + lo with ~2^-16 rel err.
// ---------------------------------------------------------------------------
__device__ __forceinline__ void split1(float x, ushort& h, ushort& l)
{
    const unsigned u = __float_as_uint(x);
    const unsigned r = (u + 0x7fffu + ((u >> 16) & 1u)) >> 16;
    h = (ushort)r;
    const float hf = __uint_as_float(r << 16);
    const float lo = x - hf;
    const unsigned u2 = __float_as_uint(lo);
    l = (ushort)((u2 + 0x7fffu + ((u2 >> 16) & 1u)) >> 16);
}

// Packed fragment address for element (r, k) of a [rows][512] matrix:
// lane l of the wave covering (r-tile, k-tile) reads elems [l*8, l*8+8).
__device__ __forceinline__ int packed_addr(int r, int k)
{
    return ((r >> 4) * 16 + (k >> 5)) * 512 + ((k >> 3) & 3) * 128 + (r & 15) * 8 + (k & 7);
}

// ---------------------------------------------------------------------------
// Split kernel: 6 arrays -> hi/lo bf16 planes in PACKED fragment layout.
// y == 6: fused edge-compaction [R15-proven].
// y == 7: colesum[b][e] = sum_c cole[b][c][e]  (8 blocks; feeds Vsum GEMV).
// ---------------------------------------------------------------------------
__global__ __launch_bounds__(256) void split_kernel(
    const float* __restrict__ rowe, const float* __restrict__ cole,
    const float* __restrict__ Wq, const float* __restrict__ Wk,
    const float* __restrict__ Wv, const float* __restrict__ Wo,
    const float* __restrict__ cost,
    ushort* __restrict__ reh, ushort* __restrict__ rel,
    ushort* __restrict__ ceh, ushort* __restrict__ cel,
    ushort* __restrict__ wqh, ushort* __restrict__ wql,
    ushort* __restrict__ wkh, ushort* __restrict__ wkl,
    ushort* __restrict__ wvh, ushort* __restrict__ wvl,
    ushort* __restrict__ woh, ushort* __restrict__ wol,
    int* __restrict__ ecb, float* __restrict__ ecwb, int* __restrict__ nEb,
    float* __restrict__ colesum)
{
    if (blockIdx.y == 6) {
        if (blockIdx.x >= MROWS / 4) return;
        const int rowIdx = blockIdx.x * 4 + (threadIdx.x >> 6);
        const int lane = threadIdx.x & 63;
        const float* crow = cost + (size_t)rowIdx * CC;
        const unsigned long long prefix = (1ull << lane) - 1ull;
        int nE = 0;
#pragma unroll
        for (int j = 0; j < 6; ++j) {
            const float cw = crow[lane + 64 * j];
            const unsigned long long mk = __ballot(cw > 0.f);
            if (cw > 0.f) {
                const int slot = nE + __popcll(mk & prefix);
                if (slot < MAXE) {
                    ecb [rowIdx * MAXE + slot] = lane + 64 * j;
                    ecwb[rowIdx * MAXE + slot] = cw;
                }
            }
            nE += __popcll(mk);
        }
        if (lane == 0) nEb[rowIdx] = (nE < MAXE) ? nE : MAXE;
        return;
    }
    if (blockIdx.y == 7) {
        // colesum: 8 blocks, (b, e-half). Coalesced 1KB reads per c-step.
        if (blockIdx.x >= 8) return;
        const int b = blockIdx.x >> 1;
        const int e = (blockIdx.x & 1) * 256 + threadIdx.x;
        float s = 0.f;
        const float* cp = cole + (size_t)b * CC * EE + e;
        for (int c = 0; c < CC; ++c) s += cp[(size_t)c * EE];
        colesum[b * EE + e] = s;
        return;
    }

    const float* src; ushort* dh; ushort* dl; int n;
    switch (blockIdx.y) {
    case 0: src = rowe; dh = reh; dl = rel; n = MROWS * EE; break;
    case 1: src = cole; dh = ceh; dl = cel; n = MROWS * EE; break;
    case 2: src = Wq;   dh = wqh; dl = wql; n = EE * EE;    break;
    case 3: src = Wk;   dh = wkh; dl = wkl; n = EE * EE;    break;
    case 4: src = Wv;   dh = wvh; dl = wvl; n = EE * EE;    break;
    default: src = Wo;  dh = woh; dl = wol; n = EE * EE;    break;
    }
    const int i4 = blockIdx.x * 256 + threadIdx.x;
    if (i4 * 4 >= n) return;
    const float4 v = ((const float4*)src)[i4];
    ushort4 hs, ls;
    split1(v.x, hs.x, ls.x);
    split1(v.y, hs.y, ls.y);
    split1(v.z, hs.z, ls.z);
    split1(v.w, hs.w, ls.w);
    const int e0 = i4 * 4;
    const int dst = packed_addr(e0 >> 9, e0 & 511);   // (k&7) in {0,4}: aligned
    *(ushort4*)(dh + dst) = hs;
    *(ushort4*)(dl + dst) = ls;
}

// ---------------------------------------------------------------------------
// Fine-grained GEMM body: 2 n-tiles per wave (16x32), split accumulators
// (6 independent MFMA chains) [R17].
// ---------------------------------------------------------------------------
__device__ __forceinline__ void gemm_bf16x3_body2(
    const ushort* __restrict__ Ahi, const ushort* __restrict__ Alo,
    const ushort* __restrict__ Whi, const ushort* __restrict__ Wlo,
    const float* __restrict__ bias, float* __restrict__ Y,
    int Mt, int Nt0)
{
    constexpr int N = 512;
    const int lane = threadIdx.x & 63;
    const int col = lane & 15, kgrp = lane >> 4;

    const ushort* pah = Ahi + (size_t)Mt * 8192 + lane * 8;
    const ushort* pal = Alo + (size_t)Mt * 8192 + lane * 8;
    const ushort* pbh = Whi + (size_t)Nt0 * 8192 + lane * 8;
    const ushort* pbl = Wlo + (size_t)Nt0 * 8192 + lane * 8;

    f32x4 a0hh = {}, a0hl = {}, a0lh = {};
    f32x4 a1hh = {}, a1hl = {}, a1lh = {};

#pragma unroll 4
    for (int kt = 0; kt < 16; ++kt) {
        const int ko = kt * 512;
        const bf16x8 ah  = *(const bf16x8*)(pah + ko);
        const bf16x8 al  = *(const bf16x8*)(pal + ko);
        const bf16x8 bh0 = *(const bf16x8*)(pbh + ko);
        const bf16x8 bh1 = *(const bf16x8*)(pbh + ko + 8192);
        const bf16x8 bl0 = *(const bf16x8*)(pbl + ko);
        const bf16x8 bl1 = *(const bf16x8*)(pbl + ko + 8192);
        a0hh = __builtin_amdgcn_mfma_f32_16x16x32_bf16(ah, bh0, a0hh, 0, 0, 0);
        a0hl = __builtin_amdgcn_mfma_f32_16x16x32_bf16(ah, bl0, a0hl, 0, 0, 0);
        a0lh = __builtin_amdgcn_mfma_f32_16x16x32_bf16(al, bh0, a0lh, 0, 0, 0);
        a1hh = __builtin_amdgcn_mfma_f32_16x16x32_bf16(ah, bh1, a1hh, 0, 0, 0);
        a1hl = __builtin_amdgcn_mfma_f32_16x16x32_bf16(ah, bl1, a1hl, 0, 0, 0);
        a1lh = __builtin_amdgcn_mfma_f32_16x16x32_bf16(al, bh1, a1lh, 0, 0, 0);
    }

    f32x4 accs[2];
#pragma unroll
    for (int j = 0; j < 4; ++j) {
        accs[0][j] = (a0hh[j] + a0hl[j]) + a0lh[j];
        accs[1][j] = (a1hh[j] + a1hl[j]) + a1lh[j];
    }
#pragma unroll
    for (int t = 0; t < 2; ++t) {
        const int n = (Nt0 + t) * 16 + col;
        const float bn = bias[n];
#pragma unroll
        for (int j = 0; j < 4; ++j) {
            const int m = Mt * 16 + kgrp * 4 + j;
            Y[m * N + n] = accs[t][j] + bn;
        }
    }
}

// ---------------------------------------------------------------------------
// qkv: grid (16, 24, 4), 256 thr. z<3: GEMMs. z==3: fused Vsum GEMV [R19].
// ---------------------------------------------------------------------------
__global__ __launch_bounds__(256) void qkv_kernel(
    const ushort* __restrict__ reh, const ushort* __restrict__ rel,
    const ushort* __restrict__ ceh, const ushort* __restrict__ cel,
    const ushort* __restrict__ wqh, const ushort* __restrict__ wql,
    const ushort* __restrict__ wkh, const ushort* __restrict__ wkl,
    const ushort* __restrict__ wvh, const ushort* __restrict__ wvl,
    const float* __restrict__ bq, const float* __restrict__ bk,
    const float* __restrict__ bv,
    const float* __restrict__ colesum, const float* __restrict__ Wvf,
    float* __restrict__ Vsum,
    float* __restrict__ Qo, float* __restrict__ Ko, float* __restrict__ Vo)
{
    __shared__ float part[256];
    if (blockIdx.z == 3) {
        if (blockIdx.y >= 4) return;
        const int h = blockIdx.x, b = blockIdx.y;
        const int d = threadIdx.x >> 3;      // 0..31
        const int pt = threadIdx.x & 7;      // 0..7
        const float* cs = colesum + b * EE + pt * 64;
        const float* wr = Wvf + (size_t)(h * DD + d) * EE + pt * 64;
        float acc = 0.f;
#pragma unroll 8
        for (int k = 0; k < 64; ++k) acc = fmaf(cs[k], wr[k], acc);
        part[threadIdx.x] = acc;
        __syncthreads();
        if (pt == 0) {
            float s = 0.f;
#pragma unroll
            for (int q = 0; q < 8; ++q) s += part[d * 8 + q];
            Vsum[(b * HH + h) * DD + d] = s + 384.f * bv[h * DD + d];
        }
        return;
    }

    const int l = blockIdx.x + (blockIdx.y << 4);
    const int a = l & 7;
    const int t = l >> 3;
    const int Bm = a * 3 + (t >> 4);
    const int Bx = t & 15;
    const int Mt = Bm * 4 + (threadIdx.x >> 6);
    const int Nt0 = Bx * 2;
    if (blockIdx.z == 0)      gemm_bf16x3_body2(reh, rel, wqh, wql, bq, Qo, Mt, Nt0);
    else if (blockIdx.z == 1) gemm_bf16x3_body2(ceh, cel, wkh, wkl, bk, Ko, Mt, Nt0);
    else                      gemm_bf16x3_body2(ceh, cel, wvh, wvl, bv, Vo, Mt, Nt0);
}

// oproj: grid (16, 24, 1), fine-grained body2.
__global__ __launch_bounds__(256) void oproj_kernel(
    const ushort* __restrict__ hbh, const ushort* __restrict__ hbl,
    const ushort* __restrict__ woh, const ushort* __restrict__ wol,
    const float* __restrict__ bo, float* __restrict__ out)
{
    const int l = blockIdx.x + (blockIdx.y << 4);
    const int a = l & 7;
    const int t = l >> 3;
    const int Bm = a * 3 + (t >> 4);
    const int Bx = t & 15;
    const int Mt = Bm * 4 + (threadIdx.x >> 6);
    const int Nt0 = Bx * 2;
    gemm_bf16x3_body2(hbh, hbl, woh, wol, bo, out, Mt, Nt0);
}

// ---------------------------------------------------------------------------
// Edge scorer: dot(q,k) -> per-head 2x16x1 MLP -> p = exp(tanh*10 - 10).
// All q / MLP params come from wave-uniform addresses -> SGPRs.
// ---------------------------------------------------------------------------
__device__ __forceinline__ float score_edge(
    int c, float cw, int b, int h,
    const float* __restrict__ qrow, const float* __restrict__ Kb,
    const float* __restrict__ w10p, const float* __restrict__ w11p,
    const float* __restrict__ b1p, const float* __restrict__ w2p, float b2h)
{
    const float* kp = Kb + ((size_t)b * CC + c) * EE + h * DD;
    float d0 = 0.f, d1 = 0.f, d2 = 0.f, d3 = 0.f;
#pragma unroll
    for (int dq = 0; dq < 8; ++dq) {
        const float4 kv = *(const float4*)(kp + dq * 4);
        d0 = fmaf(qrow[dq * 4 + 0], kv.x, d0);
        d1 = fmaf(qrow[dq * 4 + 1], kv.y, d1);
        d2 = fmaf(qrow[dq * 4 + 2], kv.z, d2);
        d3 = fmaf(qrow[dq * 4 + 3], kv.w, d3);
    }
    const float dot = ((d0 + d1) + (d2 + d3)) * 0.17677669529663687f;
    float l0 = b2h, l1 = 0.f;
#pragma unroll
    for (int mm = 0; mm < 16; mm += 2) {
        const float h0 = fmaf(dot, w10p[mm],     fmaf(cw, w11p[mm],     b1p[mm]));
        const float h1 = fmaf(dot, w10p[mm + 1], fmaf(cw, w11p[mm + 1], b1p[mm + 1]));
        l0 = fmaf(fmaxf(h0, 0.f), w2p[mm],     l0);
        l1 = fmaf(fmaxf(h1, 0.f), w2p[mm + 1], l1);
    }
    // s = tanh(l)*10; p = exp(s-10) = exp(-20/(e^{2l}+1)); bounded (no ovf).
    const float ex = __expf(2.f * (l0 + l1));
    return __expf(-20.f / (ex + 1.f));
}

// ---------------------------------------------------------------------------
// Semi-sparse attention v2: TWO 4-head waves per 128-thr block.
// The un-tried matrix cell: 4-head waves (contiguous 512B K-gather, R10's
// proven locality) + 2-wave blocks (lifts the 16-WG/CU cap) + VGPR < 64
// (via SLAB restructure of the rare nE>64 path -- drops the 5 persistent
// tail registers c1/pA1..pD1 that pinned R11's variant exactly at the
// 64-VGPR cliff). Slab [0,64) is bit-identical math to the champion for
// nE<=64 (virtually all rows); slab 2 reuses the same registers.
// Fixed-max-10 softmax:
//   out = (sum_E (p_e - e^{b-10}) V_e + e^{b-10} Vsum) / (sum p + (C-nE) e^{b-10})
// Grid (8, RR): blockIdx.x = (b,hh) -> XCD pin (R6: FETCH -55%).
// ---------------------------------------------------------------------------
__global__ __launch_bounds__(128) void attn_kernel(
    const float* __restrict__ Qb, const float* __restrict__ Kb,
    const float* __restrict__ Vb,
    const int* __restrict__ ecb, const float* __restrict__ ecwb,
    const int* __restrict__ nEb,
    const float* __restrict__ W1, const float* __restrict__ b1,
    const float* __restrict__ W2, const float* __restrict__ b2,
    const float* __restrict__ beta,
    const float* __restrict__ Vsum,
    ushort* __restrict__ Hbh, ushort* __restrict__ Hbl)
{
    const int combo = blockIdx.x;            // 0..7 -> XCD
    const int b = combo >> 1, hh = combo & 1;
    const int r = blockIdx.y;
    const int wave = threadIdx.x >> 6;       // 0..1 -> head-quad
    const int h0 = hh * 8 + wave * 4;        // this wave: heads h0..h0+3
    const int lane = threadIdx.x & 63;
    const int rowIdx = b * RR + r;

    const int nE = nEb[rowIdx];              // wave-uniform
    const float b2A = b2[h0], b2B = b2[h0 + 1], b2C = b2[h0 + 2], b2D = b2[h0 + 3];
    const float ebA = __expf(beta[h0]     - 10.f);
    const float ebB = __expf(beta[h0 + 1] - 10.f);
    const float ebC = __expf(beta[h0 + 2] - 10.f);
    const float ebD = __expf(beta[h0 + 3] - 10.f);

    const float* qA = Qb + (size_t)rowIdx * EE + h0 * DD;    // uniform -> SGPR
    const float* qB = qA + DD;
    const float* qC = qA + 2 * DD;
    const float* qD = qA + 3 * DD;
    const float* w10A = W1 + h0 * 32;
    const float* w11A = w10A + 16;
    const float* b1A  = b1 + h0 * 16;
    const float* w2A  = W2 + h0 * 16;

    const int half = lane >> 5, d = lane & 31;
    float zA = 0.f, zB = 0.f, zC = 0.f, zD = 0.f;     // per-lane Z partials
    float accA = 0.f, accB = 0.f, accC = 0.f, accD = 0.f;

    // ---- slab loop: score 64 edges, then PV them; registers reused ----
    for (int base = 0; base < nE; base += 64) {
        int c0 = 0;
        float pA0 = 0.f, pB0 = 0.f, pC0 = 0.f, pD0 = 0.f;
        const int e = base + lane;
        if (e < nE) {
            c0 = ecb[rowIdx * MAXE + e];
            const float cw = ecwb[rowIdx * MAXE + e];
            pA0 = score_edge(c0, cw, b, h0,     qA, Kb, w10A,      w11A,      b1A,      w2A,      b2A);
            pB0 = score_edge(c0, cw, b, h0 + 1, qB, Kb, w10A + 32, w11A + 32, b1A + 16, w2A + 16, b2B);
            pC0 = score_edge(c0, cw, b, h0 + 2, qC, Kb, w10A + 64, w11A + 64, b1A + 32, w2A + 32, b2C);
            pD0 = score_edge(c0, cw, b, h0 + 3, qD, Kb, w10A + 96, w11A + 96, b1A + 48, w2A + 48, b2D);
        }
        zA += pA0; zB += pB0; zC += pC0; zD += pD0;

        const float wA0 = pA0 - ebA, wB0 = pB0 - ebB, wC0 = pC0 - ebC, wD0 = pD0 - ebD;
        const int lim = (nE - base < 64) ? (nE - base) : 64;
#pragma unroll 4
        for (int eo = 0; eo < lim; eo += 2) {
            const int e2 = eo + half;
            const float wa = __shfl(wA0, e2 & 63);
            const float wb = __shfl(wB0, e2 & 63);
            const float wc = __shfl(wC0, e2 & 63);
            const float wd = __shfl(wD0, e2 & 63);
            const int   ce = __shfl(c0, e2 & 63);   // c0=0 on invalid lanes: safe
            const bool ok = e2 < lim;
            const size_t vb0 = ((size_t)b * CC + ce) * EE + h0 * DD + d;
            const float vA = Vb[vb0];
            const float vB = Vb[vb0 + DD];
            const float vC = Vb[vb0 + 2 * DD];
            const float vD = Vb[vb0 + 3 * DD];
            accA = fmaf(ok ? wa : 0.f, vA, accA);
            accB = fmaf(ok ? wb : 0.f, vB, accB);
            accC = fmaf(ok ? wc : 0.f, vC, accC);
            accD = fmaf(ok ? wd : 0.f, vD, accD);
        }
    }

    // ---- Z: one full-wave reduce at the end ----
    float ZA = zA, ZB = zB, ZC = zC, ZD = zD;
#pragma unroll
    for (int off = 1; off < 64; off <<= 1) {
        ZA += __shfl_xor(ZA, off);
        ZB += __shfl_xor(ZB, off);
        ZC += __shfl_xor(ZC, off);
        ZD += __shfl_xor(ZD, off);
    }

    accA += __shfl_xor(accA, 32);
    accB += __shfl_xor(accB, 32);
    accC += __shfl_xor(accC, 32);
    accD += __shfl_xor(accD, 32);

    // ---- epilogue: background via Vsum, write packed hi/lo bf16 ----
    if (lane < 32) {
        const float bgZ = (float)(CC - nE);
        const float invA = 1.f / (ZA + bgZ * ebA);
        const float invB = 1.f / (ZB + bgZ * ebB);
        const float invC = 1.f / (ZC + bgZ * ebC);
        const float invD = 1.f / (ZD + bgZ * ebD);
        const float* vsp = Vsum + (b * HH + h0) * DD + d;
        const float oA = (accA + ebA * vsp[0])      * invA;
        const float oB = (accB + ebB * vsp[DD])     * invB;
        const float oC = (accC + ebC * vsp[2 * DD]) * invC;
        const float oD = (accD + ebD * vsp[3 * DD]) * invD;
        const int rm = rowIdx;
        const int base_in = (d >> 3) * 128 + (rm & 15) * 8 + (d & 7);
        ushort oh, ol;
        split1(oA, oh, ol);
        int dst = ((rm >> 4) * 16 + h0) * 512 + base_in;
        Hbh[dst] = oh; Hbl[dst] = ol;
        split1(oB, oh, ol);
        dst = ((rm >> 4) * 16 + h0 + 1) * 512 + base_in;
        Hbh[dst] = oh; Hbl[dst] = ol;
        split1(oC, oh, ol);
        dst = ((rm >> 4) * 16 + h0 + 2) * 512 + base_in;
        Hbh[dst] = oh; Hbl[dst] = ol;
        split1(oD, oh, ol);
        dst = ((rm >> 4) * 16 + h0 + 3) * 512 + base_in;
        Hbh[dst] = oh; Hbl[dst] = ol;
    }
}

// ---------------------------------------------------------------------------
extern "C" void kernel_launch(void* const* d_in, const int* in_sizes, int n_in,
                              void* d_out, int out_size, void* d_ws, size_t ws_size,
                              hipStream_t stream)
{
    const float* rowe = (const float*)d_in[0];
    const float* cole = (const float*)d_in[1];
    const float* cost = (const float*)d_in[2];
    const float* Wq   = (const float*)d_in[3];
    const float* bq   = (const float*)d_in[4];
    const float* Wk   = (const float*)d_in[5];
    const float* bk   = (const float*)d_in[6];
    const float* Wv   = (const float*)d_in[7];
    const float* bv   = (const float*)d_in[8];
    const float* Wo   = (const float*)d_in[9];
    const float* bo   = (const float*)d_in[10];
    const float* W1   = (const float*)d_in[11];
    const float* b1   = (const float*)d_in[12];
    const float* W2   = (const float*)d_in[13];
    const float* b2   = (const float*)d_in[14];
    const float* beta = (const float*)d_in[15];
    float* out = (float*)d_out;

    // ---- workspace carve ----
    char* cur = (char*)d_ws;
    float* Qb   = (float*)cur; cur += (size_t)MROWS * EE * 4;
    float* Kb   = (float*)cur; cur += (size_t)MROWS * EE * 4;
    float* Vb   = (float*)cur; cur += (size_t)MROWS * EE * 4;
    float* Vsum = (float*)cur; cur += (size_t)BB * HH * DD * 4;
    ushort* reh = (ushort*)cur; cur += (size_t)MROWS * EE * 2;
    ushort* rel = (ushort*)cur; cur += (size_t)MROWS * EE * 2;
    ushort* ceh = (ushort*)cur; cur += (size_t)MROWS * EE * 2;
    ushort* cel = (ushort*)cur; cur += (size_t)MROWS * EE * 2;
    ushort* wqh = (ushort*)cur; cur += (size_t)EE * EE * 2;
    ushort* wql = (ushort*)cur; cur += (size_t)EE * EE * 2;
    ushort* wkh = (ushort*)cur; cur += (size_t)EE * EE * 2;
    ushort* wkl = (ushort*)cur; cur += (size_t)EE * EE * 2;
    ushort* wvh = (ushort*)cur; cur += (size_t)EE * EE * 2;
    ushort* wvl = (ushort*)cur; cur += (size_t)EE * EE * 2;
    ushort* woh = (ushort*)cur; cur += (size_t)EE * EE * 2;
    ushort* wol = (ushort*)cur; cur += (size_t)EE * EE * 2;
    ushort* hbh = (ushort*)cur; cur += (size_t)MROWS * EE * 2;
    ushort* hbl = (ushort*)cur; cur += (size_t)MROWS * EE * 2;
    int*    ecb = (int*)cur;   cur += (size_t)MROWS * MAXE * 4;
    float* ecwb = (float*)cur; cur += (size_t)MROWS * MAXE * 4;
    int*    nEb = (int*)cur;   cur += (size_t)MROWS * 4;
    float* colesum = (float*)cur; cur += (size_t)BB * EE * 4;

    split_kernel<<<dim3(768, 8), 256, 0, stream>>>(
        rowe, cole, Wq, Wk, Wv, Wo, cost,
        reh, rel, ceh, cel, wqh, wql, wkh, wkl, wvh, wvl, woh, wol,
        ecb, ecwb, nEb, colesum);

    dim3 g1(16, 24, 4);   // z<3: QKV GEMMs; z==3: fused Vsum GEMV (64 blocks)
    qkv_kernel<<<g1, 256, 0, stream>>>(reh, rel, ceh, cel,
                                       wqh, wql, wkh, wkl, wvh, wvl,
                                       bq, bk, bv, colesum, Wv, Vsum,
                                       Qb, Kb, Vb);

    dim3 g2(8, RR);      // x = (b,hh) -> XCD pin; y = row; 2 waves = 2 quads
    attn_kernel<<<g2, 128, 0, stream>>>(Qb, Kb, Vb, ecb, ecwb, nEb,
                                        W1, b1, W2, b2, beta, Vsum, hbh, hbl);

    dim3 g3(16, 24, 1);
    oproj_kernel<<<g3, 256, 0, stream>>>(hbh, hbl, woh, wol, bo, out);
}

// Round 21
// 78.965 us; speedup vs baseline: 1.2079x; 1.2079x over previous
//
#include <hip/hip_runtime.h>

// Problem constants
#define BB 4
#define RR 384
#define CC 384
#define EE 512
#define HH 16
#define DD 32
#define MROWS 1536   // B*R = B*C
#define MAXE 128     // edge-list stride (nE ~ 38 +- 6; 128 = 15 sigma)

typedef __attribute__((ext_vector_type(8))) short bf16x8;   // 8 bf16 = 4 VGPRs
typedef __attribute__((ext_vector_type(4))) float f32x4;

// ---------------------------------------------------------------------------
// f32 -> (hi, lo) bf16 split, RNE both times. x ~= hi + lo with ~2^-16 rel err.
// ---------------------------------------------------------------------------
__device__ __forceinline__ void split1(float x, ushort& h, ushort& l)
{
    const unsigned u = __float_as_uint(x);
    const unsigned r = (u + 0x7fffu + ((u >> 16) & 1u)) >> 16;
    h = (ushort)r;
    const float hf = __uint_as_float(r << 16);
    const float lo = x - hf;
    const unsigned u2 = __float_as_uint(lo);
    l = (ushort)((u2 + 0x7fffu + ((u2 >> 16) & 1u)) >> 16);
}

// Packed fragment address for element (r, k) of a [rows][512] matrix:
// lane l of the wave covering (r-tile, k-tile) reads elems [l*8, l*8+8).
__device__ __forceinline__ int packed_addr(int r, int k)
{
    return ((r >> 4) * 16 + (k >> 5)) * 512 + ((k >> 3) & 3) * 128 + (r & 15) * 8 + (k & 7);
}

// ---------------------------------------------------------------------------
// Split kernel: 6 arrays -> hi/lo bf16 planes in PACKED fragment layout.
// y == 6: fused edge-compaction [R15-proven].
// y == 7: colesum[b][e] = sum_c cole[b][c][e]  (8 blocks; feeds Vsum GEMV).
// ---------------------------------------------------------------------------
__global__ __launch_bounds__(256) void split_kernel(
    const float* __restrict__ rowe, const float* __restrict__ cole,
    const float* __restrict__ Wq, const float* __restrict__ Wk,
    const float* __restrict__ Wv, const float* __restrict__ Wo,
    const float* __restrict__ cost,
    ushort* __restrict__ reh, ushort* __restrict__ rel,
    ushort* __restrict__ ceh, ushort* __restrict__ cel,
    ushort* __restrict__ wqh, ushort* __restrict__ wql,
    ushort* __restrict__ wkh, ushort* __restrict__ wkl,
    ushort* __restrict__ wvh, ushort* __restrict__ wvl,
    ushort* __restrict__ woh, ushort* __restrict__ wol,
    int* __restrict__ ecb, float* __restrict__ ecwb, int* __restrict__ nEb,
    float* __restrict__ colesum)
{
    if (blockIdx.y == 6) {
        if (blockIdx.x >= MROWS / 4) return;
        const int rowIdx = blockIdx.x * 4 + (threadIdx.x >> 6);
        const int lane = threadIdx.x & 63;
        const float* crow = cost + (size_t)rowIdx * CC;
        const unsigned long long prefix = (1ull << lane) - 1ull;
        int nE = 0;
#pragma unroll
        for (int j = 0; j < 6; ++j) {
            const float cw = crow[lane + 64 * j];
            const unsigned long long mk = __ballot(cw > 0.f);
            if (cw > 0.f) {
                const int slot = nE + __popcll(mk & prefix);
                if (slot < MAXE) {
                    ecb [rowIdx * MAXE + slot] = lane + 64 * j;
                    ecwb[rowIdx * MAXE + slot] = cw;
                }
            }
            nE += __popcll(mk);
        }
        if (lane == 0) nEb[rowIdx] = (nE < MAXE) ? nE : MAXE;
        return;
    }
    if (blockIdx.y == 7) {
        // colesum: 8 blocks, (b, e-half). Coalesced 1KB reads per c-step.
        if (blockIdx.x >= 8) return;
        const int b = blockIdx.x >> 1;
        const int e = (blockIdx.x & 1) * 256 + threadIdx.x;
        float s = 0.f;
        const float* cp = cole + (size_t)b * CC * EE + e;
        for (int c = 0; c < CC; ++c) s += cp[(size_t)c * EE];
        colesum[b * EE + e] = s;
        return;
    }

    const float* src; ushort* dh; ushort* dl; int n;
    switch (blockIdx.y) {
    case 0: src = rowe; dh = reh; dl = rel; n = MROWS * EE; break;
    case 1: src = cole; dh = ceh; dl = cel; n = MROWS * EE; break;
    case 2: src = Wq;   dh = wqh; dl = wql; n = EE * EE;    break;
    case 3: src = Wk;   dh = wkh; dl = wkl; n = EE * EE;    break;
    case 4: src = Wv;   dh = wvh; dl = wvl; n = EE * EE;    break;
    default: src = Wo;  dh = woh; dl = wol; n = EE * EE;    break;
    }
    const int i4 = blockIdx.x * 256 + threadIdx.x;
    if (i4 * 4 >= n) return;
    const float4 v = ((const float4*)src)[i4];
    ushort4 hs, ls;
    split1(v.x, hs.x, ls.x);
    split1(v.y, hs.y, ls.y);
    split1(v.z, hs.z, ls.z);
    split1(v.w, hs.w, ls.w);
    const int e0 = i4 * 4;
    const int dst = packed_addr(e0 >> 9, e0 & 511);   // (k&7) in {0,4}: aligned
    *(ushort4*)(dh + dst) = hs;
    *(ushort4*)(dl + dst) = ls;
}

// ---------------------------------------------------------------------------
// Fine-grained GEMM body: 2 n-tiles per wave (16x32), split accumulators
// (6 independent MFMA chains) [R17].
// ---------------------------------------------------------------------------
__device__ __forceinline__ void gemm_bf16x3_body2(
    const ushort* __restrict__ Ahi, const ushort* __restrict__ Alo,
    const ushort* __restrict__ Whi, const ushort* __restrict__ Wlo,
    const float* __restrict__ bias, float* __restrict__ Y,
    int Mt, int Nt0)
{
    constexpr int N = 512;
    const int lane = threadIdx.x & 63;
    const int col = lane & 15, kgrp = lane >> 4;

    const ushort* pah = Ahi + (size_t)Mt * 8192 + lane * 8;
    const ushort* pal = Alo + (size_t)Mt * 8192 + lane * 8;
    const ushort* pbh = Whi + (size_t)Nt0 * 8192 + lane * 8;
    const ushort* pbl = Wlo + (size_t)Nt0 * 8192 + lane * 8;

    f32x4 a0hh = {}, a0hl = {}, a0lh = {};
    f32x4 a1hh = {}, a1hl = {}, a1lh = {};

#pragma unroll 4
    for (int kt = 0; kt < 16; ++kt) {
        const int ko = kt * 512;
        const bf16x8 ah  = *(const bf16x8*)(pah + ko);
        const bf16x8 al  = *(const bf16x8*)(pal + ko);
        const bf16x8 bh0 = *(const bf16x8*)(pbh + ko);
        const bf16x8 bh1 = *(const bf16x8*)(pbh + ko + 8192);
        const bf16x8 bl0 = *(const bf16x8*)(pbl + ko);
        const bf16x8 bl1 = *(const bf16x8*)(pbl + ko + 8192);
        a0hh = __builtin_amdgcn_mfma_f32_16x16x32_bf16(ah, bh0, a0hh, 0, 0, 0);
        a0hl = __builtin_amdgcn_mfma_f32_16x16x32_bf16(ah, bl0, a0hl, 0, 0, 0);
        a0lh = __builtin_amdgcn_mfma_f32_16x16x32_bf16(al, bh0, a0lh, 0, 0, 0);
        a1hh = __builtin_amdgcn_mfma_f32_16x16x32_bf16(ah, bh1, a1hh, 0, 0, 0);
        a1hl = __builtin_amdgcn_mfma_f32_16x16x32_bf16(ah, bl1, a1hl, 0, 0, 0);
        a1lh = __builtin_amdgcn_mfma_f32_16x16x32_bf16(al, bh1, a1lh, 0, 0, 0);
    }

    f32x4 accs[2];
#pragma unroll
    for (int j = 0; j < 4; ++j) {
        accs[0][j] = (a0hh[j] + a0hl[j]) + a0lh[j];
        accs[1][j] = (a1hh[j] + a1hl[j]) + a1lh[j];
    }
#pragma unroll
    for (int t = 0; t < 2; ++t) {
        const int n = (Nt0 + t) * 16 + col;
        const float bn = bias[n];
#pragma unroll
        for (int j = 0; j < 4; ++j) {
            const int m = Mt * 16 + kgrp * 4 + j;
            Y[m * N + n] = accs[t][j] + bn;
        }
    }
}

// ---------------------------------------------------------------------------
// qkv: grid (16, 24, 4), 256 thr. z<3: GEMMs. z==3: fused Vsum GEMV [R19].
// ---------------------------------------------------------------------------
__global__ __launch_bounds__(256) void qkv_kernel(
    const ushort* __restrict__ reh, const ushort* __restrict__ rel,
    const ushort* __restrict__ ceh, const ushort* __restrict__ cel,
    const ushort* __restrict__ wqh, const ushort* __restrict__ wql,
    const ushort* __restrict__ wkh, const ushort* __restrict__ wkl,
    const ushort* __restrict__ wvh, const ushort* __restrict__ wvl,
    const float* __restrict__ bq, const float* __restrict__ bk,
    const float* __restrict__ bv,
    const float* __restrict__ colesum, const float* __restrict__ Wvf,
    float* __restrict__ Vsum,
    float* __restrict__ Qo, float* __restrict__ Ko, float* __restrict__ Vo)
{
    __shared__ float part[256];
    if (blockIdx.z == 3) {
        if (blockIdx.y >= 4) return;
        const int h = blockIdx.x, b = blockIdx.y;
        const int d = threadIdx.x >> 3;      // 0..31
        const int pt = threadIdx.x & 7;      // 0..7
        const float* cs = colesum + b * EE + pt * 64;
        const float* wr = Wvf + (size_t)(h * DD + d) * EE + pt * 64;
        float acc = 0.f;
#pragma unroll 8
        for (int k = 0; k < 64; ++k) acc = fmaf(cs[k], wr[k], acc);
        part[threadIdx.x] = acc;
        __syncthreads();
        if (pt == 0) {
            float s = 0.f;
#pragma unroll
            for (int q = 0; q < 8; ++q) s += part[d * 8 + q];
            Vsum[(b * HH + h) * DD + d] = s + 384.f * bv[h * DD + d];
        }
        return;
    }

    const int l = blockIdx.x + (blockIdx.y << 4);
    const int a = l & 7;
    const int t = l >> 3;
    const int Bm = a * 3 + (t >> 4);
    const int Bx = t & 15;
    const int Mt = Bm * 4 + (threadIdx.x >> 6);
    const int Nt0 = Bx * 2;
    if (blockIdx.z == 0)      gemm_bf16x3_body2(reh, rel, wqh, wql, bq, Qo, Mt, Nt0);
    else if (blockIdx.z == 1) gemm_bf16x3_body2(ceh, cel, wkh, wkl, bk, Ko, Mt, Nt0);
    else                      gemm_bf16x3_body2(ceh, cel, wvh, wvl, bv, Vo, Mt, Nt0);
}

// oproj: grid (16, 24, 1), fine-grained body2.
__global__ __launch_bounds__(256) void oproj_kernel(
    const ushort* __restrict__ hbh, const ushort* __restrict__ hbl,
    const ushort* __restrict__ woh, const ushort* __restrict__ wol,
    const float* __restrict__ bo, float* __restrict__ out)
{
    const int l = blockIdx.x + (blockIdx.y << 4);
    const int a = l & 7;
    const int t = l >> 3;
    const int Bm = a * 3 + (t >> 4);
    const int Bx = t & 15;
    const int Mt = Bm * 4 + (threadIdx.x >> 6);
    const int Nt0 = Bx * 2;
    gemm_bf16x3_body2(hbh, hbl, woh, wol, bo, out, Mt, Nt0);
}

// ---------------------------------------------------------------------------
// Edge scorer: dot(q,k) -> per-head 2x16x1 MLP -> p = exp(tanh*10 - 10).
// All q / MLP params come from wave-uniform addresses -> SGPRs.
// ---------------------------------------------------------------------------
__device__ __forceinline__ float score_edge(
    int c, float cw, int b, int h,
    const float* __restrict__ qrow, const float* __restrict__ Kb,
    const float* __restrict__ w10p, const float* __restrict__ w11p,
    const float* __restrict__ b1p, const float* __restrict__ w2p, float b2h)
{
    const float* kp = Kb + ((size_t)b * CC + c) * EE + h * DD;
    float d0 = 0.f, d1 = 0.f, d2 = 0.f, d3 = 0.f;
#pragma unroll
    for (int dq = 0; dq < 8; ++dq) {
        const float4 kv = *(const float4*)(kp + dq * 4);
        d0 = fmaf(qrow[dq * 4 + 0], kv.x, d0);
        d1 = fmaf(qrow[dq * 4 + 1], kv.y, d1);
        d2 = fmaf(qrow[dq * 4 + 2], kv.z, d2);
        d3 = fmaf(qrow[dq * 4 + 3], kv.w, d3);
    }
    const float dot = ((d0 + d1) + (d2 + d3)) * 0.17677669529663687f;
    float l0 = b2h, l1 = 0.f;
#pragma unroll
    for (int mm = 0; mm < 16; mm += 2) {
        const float h0 = fmaf(dot, w10p[mm],     fmaf(cw, w11p[mm],     b1p[mm]));
        const float h1 = fmaf(dot, w10p[mm + 1], fmaf(cw, w11p[mm + 1], b1p[mm + 1]));
        l0 = fmaf(fmaxf(h0, 0.f), w2p[mm],     l0);
        l1 = fmaf(fmaxf(h1, 0.f), w2p[mm + 1], l1);
    }
    // s = tanh(l)*10; p = exp(s-10) = exp(-20/(e^{2l}+1)); bounded (no ovf).
    const float ex = __expf(2.f * (l0 + l1));
    return __expf(-20.f / (ex + 1.f));
}

// ---------------------------------------------------------------------------
// Semi-sparse attention: champion (R10 structure). ONE WAVE per
// (b,r,head-quad), PV loop unroll 4. R20 closed the structure matrix:
// 4-head locality and sub-64-VGPR occupancy are mutually exclusive; this
// 1-wave/4-head shape is the measured optimum. Fixed-max-10 softmax:
//   out = (sum_E (p_e - e^{b-10}) V_e + e^{b-10} Vsum) / (sum p + (C-nE) e^{b-10})
// Grid (8, RR, 2): blockIdx.x = (b,hh) -> XCD pin (R6: FETCH -55%).
// ---------------------------------------------------------------------------
__global__ __launch_bounds__(64) void attn_kernel(
    const float* __restrict__ Qb, const float* __restrict__ Kb,
    const float* __restrict__ Vb,
    const int* __restrict__ ecb, const float* __restrict__ ecwb,
    const int* __restrict__ nEb,
    const float* __restrict__ W1, const float* __restrict__ b1,
    const float* __restrict__ W2, const float* __restrict__ b2,
    const float* __restrict__ beta,
    const float* __restrict__ Vsum,
    ushort* __restrict__ Hbh, ushort* __restrict__ Hbl)
{
    const int combo = blockIdx.x;            // 0..7 -> XCD
    const int b = combo >> 1, hh = combo & 1;
    const int r = blockIdx.y;
    const int h0 = hh * 8 + blockIdx.z * 4;  // this wave: heads h0..h0+3
    const int lane = threadIdx.x;
    const int rowIdx = b * RR + r;

    const int nE = nEb[rowIdx];              // wave-uniform
    const float b2A = b2[h0], b2B = b2[h0 + 1], b2C = b2[h0 + 2], b2D = b2[h0 + 3];
    const float ebA = __expf(beta[h0]     - 10.f);
    const float ebB = __expf(beta[h0 + 1] - 10.f);
    const float ebC = __expf(beta[h0 + 2] - 10.f);
    const float ebD = __expf(beta[h0 + 3] - 10.f);

    const float* qA = Qb + (size_t)rowIdx * EE + h0 * DD;    // uniform -> SGPR
    const float* qB = qA + DD;
    const float* qC = qA + 2 * DD;
    const float* qD = qA + 3 * DD;
    const float* w10A = W1 + h0 * 32;
    const float* w11A = w10A + 16;
    const float* b1A  = b1 + h0 * 16;
    const float* w2A  = W2 + h0 * 16;

    // ---- scoring: lane e = edge e, 4 heads (independent chains) ----
    int c0 = 0, c1 = 0;
    float pA0 = 0.f, pB0 = 0.f, pC0 = 0.f, pD0 = 0.f;
    float pA1 = 0.f, pB1 = 0.f, pC1 = 0.f, pD1 = 0.f;
    if (lane < nE) {
        c0 = ecb[rowIdx * MAXE + lane];
        const float cw = ecwb[rowIdx * MAXE + lane];
        pA0 = score_edge(c0, cw, b, h0,     qA, Kb, w10A,      w11A,      b1A,      w2A,      b2A);
        pB0 = score_edge(c0, cw, b, h0 + 1, qB, Kb, w10A + 32, w11A + 32, b1A + 16, w2A + 16, b2B);
        pC0 = score_edge(c0, cw, b, h0 + 2, qC, Kb, w10A + 64, w11A + 64, b1A + 32, w2A + 32, b2C);
        pD0 = score_edge(c0, cw, b, h0 + 3, qD, Kb, w10A + 96, w11A + 96, b1A + 48, w2A + 48, b2D);
    }
    if (nE > 64) {                           // wave-uniform rare branch
        const int e1 = lane + 64;
        if (e1 < nE) {
            c1 = ecb[rowIdx * MAXE + e1];
            const float cw = ecwb[rowIdx * MAXE + e1];
            pA1 = score_edge(c1, cw, b, h0,     qA, Kb, w10A,      w11A,      b1A,      w2A,      b2A);
            pB1 = score_edge(c1, cw, b, h0 + 1, qB, Kb, w10A + 32, w11A + 32, b1A + 16, w2A + 16, b2B);
            pC1 = score_edge(c1, cw, b, h0 + 2, qC, Kb, w10A + 64, w11A + 64, b1A + 32, w2A + 32, b2C);
            pD1 = score_edge(c1, cw, b, h0 + 3, qD, Kb, w10A + 96, w11A + 96, b1A + 48, w2A + 48, b2D);
        }
    }

    // ---- Z: full-wave reduce, 4 heads ----
    float ZA = pA0 + pA1, ZB = pB0 + pB1, ZC = pC0 + pC1, ZD = pD0 + pD1;
#pragma unroll
    for (int off = 1; off < 64; off <<= 1) {
        ZA += __shfl_xor(ZA, off);
        ZB += __shfl_xor(ZB, off);
        ZC += __shfl_xor(ZC, off);
        ZD += __shfl_xor(ZD, off);
    }

    // ---- PV: 2 edges/iter, 4 heads; unroll 4 -> ~16 loads in flight ----
    const int half = lane >> 5, d = lane & 31;
    const float wA0 = pA0 - ebA, wB0 = pB0 - ebB, wC0 = pC0 - ebC, wD0 = pD0 - ebD;
    float accA = 0.f, accB = 0.f, accC = 0.f, accD = 0.f;
    const int lim0 = (nE < 64) ? nE : 64;
#pragma unroll 4
    for (int eo = 0; eo < lim0; eo += 2) {
        const int e = eo + half;
        const float wa = __shfl(wA0, e & 63);
        const float wb = __shfl(wB0, e & 63);
        const float wc = __shfl(wC0, e & 63);
        const float wd = __shfl(wD0, e & 63);
        const int   ce = __shfl(c0, e & 63);   // c0=0 on invalid lanes: safe
        const bool ok = e < lim0;
        const size_t vb0 = ((size_t)b * CC + ce) * EE + h0 * DD + d;
        const float vA = Vb[vb0];
        const float vB = Vb[vb0 + DD];
        const float vC = Vb[vb0 + 2 * DD];
        const float vD = Vb[vb0 + 3 * DD];
        accA = fmaf(ok ? wa : 0.f, vA, accA);
        accB = fmaf(ok ? wb : 0.f, vB, accB);
        accC = fmaf(ok ? wc : 0.f, vC, accC);
        accD = fmaf(ok ? wd : 0.f, vD, accD);
    }
    if (nE > 64) {
        const float wA1 = pA1 - ebA, wB1 = pB1 - ebB, wC1 = pC1 - ebC, wD1 = pD1 - ebD;
        for (int eo = 64; eo < nE; eo += 2) {
            const int e = eo + half;
            const float wa = __shfl(wA1, (e - 64) & 63);
            const float wb = __shfl(wB1, (e - 64) & 63);
            const float wc = __shfl(wC1, (e - 64) & 63);
            const float wd = __shfl(wD1, (e - 64) & 63);
            const int   ce = __shfl(c1, (e - 64) & 63);
            const bool ok = e < nE;
            const size_t vb0 = ((size_t)b * CC + ce) * EE + h0 * DD + d;
            const float vA = Vb[vb0];
            const float vB = Vb[vb0 + DD];
            const float vC = Vb[vb0 + 2 * DD];
            const float vD = Vb[vb0 + 3 * DD];
            accA = fmaf(ok ? wa : 0.f, vA, accA);
            accB = fmaf(ok ? wb : 0.f, vB, accB);
            accC = fmaf(ok ? wc : 0.f, vC, accC);
            accD = fmaf(ok ? wd : 0.f, vD, accD);
        }
    }
    accA += __shfl_xor(accA, 32);
    accB += __shfl_xor(accB, 32);
    accC += __shfl_xor(accC, 32);
    accD += __shfl_xor(accD, 32);

    // ---- epilogue: background via Vsum, write packed hi/lo bf16 ----
    if (lane < 32) {
        const float bgZ = (float)(CC - nE);
        const float invA = 1.f / (ZA + bgZ * ebA);
        const float invB = 1.f / (ZB + bgZ * ebB);
        const float invC = 1.f / (ZC + bgZ * ebC);
        const float invD = 1.f / (ZD + bgZ * ebD);
        const float* vsp = Vsum + (b * HH + h0) * DD + d;
        const float oA = (accA + ebA * vsp[0])      * invA;
        const float oB = (accB + ebB * vsp[DD])     * invB;
        const float oC = (accC + ebC * vsp[2 * DD]) * invC;
        const float oD = (accD + ebD * vsp[3 * DD]) * invD;
        const int rm = rowIdx;
        const int base_in = (d >> 3) * 128 + (rm & 15) * 8 + (d & 7);
        ushort oh, ol;
        split1(oA, oh, ol);
        int dst = ((rm >> 4) * 16 + h0) * 512 + base_in;
        Hbh[dst] = oh; Hbl[dst] = ol;
        split1(oB, oh, ol);
        dst = ((rm >> 4) * 16 + h0 + 1) * 512 + base_in;
        Hbh[dst] = oh; Hbl[dst] = ol;
        split1(oC, oh, ol);
        dst = ((rm >> 4) * 16 + h0 + 2) * 512 + base_in;
        Hbh[dst] = oh; Hbl[dst] = ol;
        split1(oD, oh, ol);
        dst = ((rm >> 4) * 16 + h0 + 3) * 512 + base_in;
        Hbh[dst] = oh; Hbl[dst] = ol;
    }
}

// ---------------------------------------------------------------------------
extern "C" void kernel_launch(void* const* d_in, const int* in_sizes, int n_in,
                              void* d_out, int out_size, void* d_ws, size_t ws_size,
                              hipStream_t stream)
{
    const float* rowe = (const float*)d_in[0];
    const float* cole = (const float*)d_in[1];
    const float* cost = (const float*)d_in[2];
    const float* Wq   = (const float*)d_in[3];
    const float* bq   = (const float*)d_in[4];
    const float* Wk   = (const float*)d_in[5];
    const float* bk   = (const float*)d_in[6];
    const float* Wv   = (const float*)d_in[7];
    const float* bv   = (const float*)d_in[8];
    const float* Wo   = (const float*)d_in[9];
    const float* bo   = (const float*)d_in[10];
    const float* W1   = (const float*)d_in[11];
    const float* b1   = (const float*)d_in[12];
    const float* W2   = (const float*)d_in[13];
    const float* b2   = (const float*)d_in[14];
    const float* beta = (const float*)d_in[15];
    float* out = (float*)d_out;

    // ---- workspace carve ----
    char* cur = (char*)d_ws;
    float* Qb   = (float*)cur; cur += (size_t)MROWS * EE * 4;
    float* Kb   = (float*)cur; cur += (size_t)MROWS * EE * 4;
    float* Vb   = (float*)cur; cur += (size_t)MROWS * EE * 4;
    float* Vsum = (float*)cur; cur += (size_t)BB * HH * DD * 4;
    ushort* reh = (ushort*)cur; cur += (size_t)MROWS * EE * 2;
    ushort* rel = (ushort*)cur; cur += (size_t)MROWS * EE * 2;
    ushort* ceh = (ushort*)cur; cur += (size_t)MROWS * EE * 2;
    ushort* cel = (ushort*)cur; cur += (size_t)MROWS * EE * 2;
    ushort* wqh = (ushort*)cur; cur += (size_t)EE * EE * 2;
    ushort* wql = (ushort*)cur; cur += (size_t)EE * EE * 2;
    ushort* wkh = (ushort*)cur; cur += (size_t)EE * EE * 2;
    ushort* wkl = (ushort*)cur; cur += (size_t)EE * EE * 2;
    ushort* wvh = (ushort*)cur; cur += (size_t)EE * EE * 2;
    ushort* wvl = (ushort*)cur; cur += (size_t)EE * EE * 2;
    ushort* woh = (ushort*)cur; cur += (size_t)EE * EE * 2;
    ushort* wol = (ushort*)cur; cur += (size_t)EE * EE * 2;
    ushort* hbh = (ushort*)cur; cur += (size_t)MROWS * EE * 2;
    ushort* hbl = (ushort*)cur; cur += (size_t)MROWS * EE * 2;
    int*    ecb = (int*)cur;   cur += (size_t)MROWS * MAXE * 4;
    float* ecwb = (float*)cur; cur += (size_t)MROWS * MAXE * 4;
    int*    nEb = (int*)cur;   cur += (size_t)MROWS * 4;
    float* colesum = (float*)cur; cur += (size_t)BB * EE * 4;

    split_kernel<<<dim3(768, 8), 256, 0, stream>>>(
        rowe, cole, Wq, Wk, Wv, Wo, cost,
        reh, rel, ceh, cel, wqh, wql, wkh, wkl, wvh, wvl, woh, wol,
        ecb, ecwb, nEb, colesum);

    dim3 g1(16, 24, 4);   // z<3: QKV GEMMs; z==3: fused Vsum GEMV (64 blocks)
    qkv_kernel<<<g1, 256, 0, stream>>>(reh, rel, ceh, cel,
                                       wqh, wql, wkh, wkl, wvh, wvl,
                                       bq, bk, bv, colesum, Wv, Vsum,
                                       Qb, Kb, Vb);

    dim3 g2(8, RR, 2);   // x = (b,hh) -> XCD pin; y = row; z = head-quad
    attn_kernel<<<g2, 64, 0, stream>>>(Qb, Kb, Vb, ecb, ecwb, nEb,
                                       W1, b1, W2, b2, beta, Vsum, hbh, hbl);

    dim3 g3(16, 24, 1);
    oproj_kernel<<<g3, 256, 0, stream>>>(hbh, hbl, woh, wol, bo, out);
}